// Round 3
// baseline (1030.987 us; speedup 1.0000x reference)
//
#include <hip/hip_runtime.h>

#define NN 100000      // nodes
#define NE 800000      // edges
#define DD 128         // hidden dim
#define NL 3           // layers
#define NC 10          // classes
#define NG 64          // graphs
#define EPSV 1e-5f
#define SCAN_CHUNK 1024
#define NB_SCAN ((NN + SCAN_CHUNK - 1) / SCAN_CHUNK)   // 98
#define TM 32          // nodes per GEMM tile

// ---------------- CSR build ----------------

__global__ void k_hist(const int* __restrict__ ei, int* __restrict__ cnt) {
    int e = blockIdx.x * 256 + threadIdx.x;
    if (e < NE) atomicAdd(&cnt[ei[NE + e]], 1);
}

__global__ void k_scan_part(const int* __restrict__ cnt, int* __restrict__ part) {
    __shared__ int lds[256];
    int base = blockIdx.x * SCAN_CHUNK + threadIdx.x * 4;
    int s = 0;
    for (int i = 0; i < 4; i++) { int idx = base + i; if (idx < NN) s += cnt[idx]; }
    lds[threadIdx.x] = s; __syncthreads();
    for (int off = 128; off > 0; off >>= 1) {
        if (threadIdx.x < off) lds[threadIdx.x] += lds[threadIdx.x + off];
        __syncthreads();
    }
    if (threadIdx.x == 0) part[blockIdx.x] = lds[0];
}

__global__ void k_scan_top(int* part, int nb) {
    __shared__ int lds[128];
    int t = threadIdx.x;
    int v = (t < nb) ? part[t] : 0;
    lds[t] = v; __syncthreads();
    for (int off = 1; off < 128; off <<= 1) {
        int add = (t >= off) ? lds[t - off] : 0;
        __syncthreads();
        lds[t] += add;
        __syncthreads();
    }
    if (t < nb) part[t] = lds[t] - v;   // exclusive
}

__global__ void k_scan_final(const int* __restrict__ part, int* __restrict__ cnt,
                             int* __restrict__ offs, float* __restrict__ deg_inv) {
    __shared__ int lds[256];
    int t = threadIdx.x;
    int base = blockIdx.x * SCAN_CHUNK + t * 4;
    int v[4]; int s = 0;
    for (int i = 0; i < 4; i++) { int idx = base + i; v[i] = (idx < NN) ? cnt[idx] : 0; s += v[i]; }
    lds[t] = s; __syncthreads();
    for (int o = 1; o < 256; o <<= 1) {
        int add = (t >= o) ? lds[t - o] : 0;
        __syncthreads();
        lds[t] += add;
        __syncthreads();
    }
    int excl = lds[t] - s + part[blockIdx.x];
    for (int i = 0; i < 4; i++) {
        int idx = base + i;
        if (idx < NN) {
            offs[idx] = excl;
            cnt[idx]  = excl;   // becomes the fill cursor
            deg_inv[idx] = 1.0f / (float)max(v[i], 1);
            excl += v[i];
        }
    }
    if (blockIdx.x == 0 && t == 0) offs[NN] = NE;
}

__global__ void k_fill(const int* __restrict__ ei, int* __restrict__ cur, int* __restrict__ esrc) {
    int e = blockIdx.x * 256 + threadIdx.x;
    if (e < NE) {
        int d = ei[NE + e];
        int slot = atomicAdd(&cur[d], 1);
        esrc[slot] = ei[e];
    }
}

// ---------------- aggregation: one block (128 thr) per node ----------------

__global__ __launch_bounds__(128) void k_agg(const float* __restrict__ h,
                                             const int* __restrict__ offs,
                                             const int* __restrict__ esrc,
                                             const float* __restrict__ deg_inv,
                                             float* __restrict__ outp) {
    int n = blockIdx.x;
    int t = threadIdx.x;
    int s0 = offs[n], s1 = offs[n + 1];
    float acc = 0.f;
    for (int j = s0; j < s1; ++j) {
        int s = esrc[j];
        acc += h[(size_t)s * DD + t];
    }
    outp[(size_t)n * DD + t] = acc * deg_inv[n];
}

// ---------------- fused GEMM: out = agg@Wl + bl + h@Wr, plus BN partial sums --------

__global__ __launch_bounds__(256) void k_gemm(
    const float* __restrict__ agg, const float* __restrict__ h,
    const float* __restrict__ Wl, const float* __restrict__ bl,
    const float* __restrict__ Wr,
    float* __restrict__ outp, float* __restrict__ bn /* [2][DD] sums */) {

    __shared__ float aR[TM][132];   // padded rows: scalar reads broadcast conflict-free
    __shared__ float hR[TM][132];
    __shared__ float wl[32][DD];    // k-chunk of Wl
    __shared__ float wr[32][DD];
    __shared__ float red[8][DD];

    int tile = blockIdx.x;
    int n0 = tile * TM;
    int tid = threadIdx.x;
    int fg = tid & 31;    // features 4*fg .. 4*fg+3
    int ng = tid >> 5;    // nodes 4*ng .. 4*ng+3

    // stage node tiles (linear float4 mapping, coalesced, ~conflict-free)
    for (int i = 0; i < 4; i++) {
        int idx = tid + 256 * i;       // 0..1023 float4 slots (32 rows x 32 f4-cols)
        int r = idx >> 5;              // row 0..31
        int c = idx & 31;              // float4 col 0..31
        float4 a4 = *(const float4*)(agg + (size_t)(n0 + r) * DD + c * 4);
        float4 h4 = *(const float4*)(h   + (size_t)(n0 + r) * DD + c * 4);
        *(float4*)&aR[r][c * 4] = a4;
        *(float4*)&hR[r][c * 4] = h4;
    }

    float acc[4][4] = {{0.f}};

    for (int kt = 0; kt < 4; ++kt) {
        __syncthreads();
        // stage weight chunk rows kt*32 .. kt*32+31
        // 32 rows x 128 floats = 4096 floats = 1024 float4 slots -> 4 iters of 256 thr
        for (int i = 0; i < 4; i++) {
            int idx = tid + 256 * i;   // 0..1023
            int r = idx >> 5;          // 0..31
            int c = idx & 31;          // 0..31 (float4 col)
            *(float4*)&wl[r][c * 4] = *(const float4*)(Wl + (size_t)(kt * 32 + r) * DD + c * 4);
            *(float4*)&wr[r][c * 4] = *(const float4*)(Wr + (size_t)(kt * 32 + r) * DD + c * 4);
        }
        __syncthreads();
        #pragma unroll 4
        for (int kk = 0; kk < 32; ++kk) {
            int k = kt * 32 + kk;
            float4 wlv = *(const float4*)&wl[kk][fg * 4];
            float4 wrv = *(const float4*)&wr[kk][fg * 4];
            float wlj[4] = {wlv.x, wlv.y, wlv.z, wlv.w};
            float wrj[4] = {wrv.x, wrv.y, wrv.z, wrv.w};
            #pragma unroll
            for (int i = 0; i < 4; i++) {
                float ai = aR[4 * ng + i][k];
                float hi = hR[4 * ng + i][k];
                #pragma unroll
                for (int j = 0; j < 4; j++)
                    acc[i][j] += ai * wlj[j] + hi * wrj[j];
            }
        }
    }

    // epilogue: bias, store (in place over agg), BN partial sums
    float4 b4 = *(const float4*)&bl[fg * 4];
    float bj[4] = {b4.x, b4.y, b4.z, b4.w};
    float bsum[4] = {0, 0, 0, 0}, bsq[4] = {0, 0, 0, 0};
    for (int i = 0; i < 4; i++) {
        int n = n0 + 4 * ng + i;
        float o[4];
        #pragma unroll
        for (int j = 0; j < 4; j++) {
            o[j] = acc[i][j] + bj[j];
            bsum[j] += o[j];
            bsq[j] += o[j] * o[j];
        }
        float4 o4 = {o[0], o[1], o[2], o[3]};
        *(float4*)&outp[(size_t)n * DD + fg * 4] = o4;
    }
    __syncthreads();
    for (int j = 0; j < 4; j++) red[ng][fg * 4 + j] = bsum[j];
    __syncthreads();
    if (tid < DD) {
        float s = 0;
        for (int g = 0; g < 8; g++) s += red[g][tid];
        atomicAdd(&bn[tid], s);
    }
    __syncthreads();
    for (int j = 0; j < 4; j++) red[ng][fg * 4 + j] = bsq[j];
    __syncthreads();
    if (tid < DD) {
        float s = 0;
        for (int g = 0; g < 8; g++) s += red[g][tid];
        atomicAdd(&bn[DD + tid], s);
    }
}

// ---------------- BN finalize + apply ----------------

__global__ void k_bnfinal(const float* __restrict__ bn, const float* __restrict__ gamma,
                          const float* __restrict__ beta, float* __restrict__ ss) {
    int f = threadIdx.x;
    float mu = bn[f] / (float)NN;
    float var = bn[DD + f] / (float)NN - mu * mu;
    var = fmaxf(var, 0.f);
    float sc = gamma[f] * rsqrtf(var + EPSV);
    ss[f] = sc;
    ss[DD + f] = beta[f] - mu * sc;
}

__global__ __launch_bounds__(256) void k_bnrelu(float* __restrict__ hbuf, const float* __restrict__ ss) {
    size_t i = (size_t)blockIdx.x * 256 + threadIdx.x;   // float4 index, NN*DD/4 total
    int f4 = (int)(i & 31);
    float4 v = ((float4*)hbuf)[i];
    float4 sc = ((const float4*)ss)[f4];
    float4 sh = ((const float4*)(ss + DD))[f4];
    v.x = fmaxf(v.x * sc.x + sh.x, 0.f);
    v.y = fmaxf(v.y * sc.y + sh.y, 0.f);
    v.z = fmaxf(v.z * sc.z + sh.z, 0.f);
    v.w = fmaxf(v.w * sc.w + sh.w, 0.f);
    ((float4*)hbuf)[i] = v;
}

// ---------------- pooling + classifier ----------------

__device__ int lbound(const int* __restrict__ a, int v) {
    int lo = 0, hi = NN;
    while (lo < hi) { int m = (lo + hi) >> 1; if (a[m] < v) lo = m + 1; else hi = m; }
    return lo;
}

__global__ __launch_bounds__(128) void k_pool(const float* __restrict__ hbuf,
                                              const int* __restrict__ batch,
                                              float* __restrict__ pool, int* __restrict__ pcnt) {
    int g = blockIdx.x >> 2;
    int c = blockIdx.x & 3;
    int s = lbound(batch, g);
    int e = lbound(batch, g + 1);
    int len = e - s;
    int s2 = s + (int)(((long long)len * c) >> 2);
    int e2 = s + (int)(((long long)len * (c + 1)) >> 2);
    int t = threadIdx.x;
    float acc = 0.f;
    for (int n = s2; n < e2; ++n) acc += hbuf[(size_t)n * DD + t];
    atomicAdd(&pool[g * DD + t], acc);
    if (t == 0 && c == 0) pcnt[g] = len;
}

__global__ __launch_bounds__(128) void k_cls(const float* __restrict__ pool, const int* __restrict__ pcnt,
                                             const float* __restrict__ Wc, const float* __restrict__ bc,
                                             float* __restrict__ outp) {
    __shared__ float emb[DD];
    int g = blockIdx.x; int t = threadIdx.x;
    float cnt = fmaxf((float)pcnt[g], 1.f);
    emb[t] = pool[g * DD + t] / cnt;
    __syncthreads();
    if (t < NC) {
        float s = bc[t];
        for (int k = 0; k < DD; k++) s += emb[k] * Wc[k * NC + t];
        outp[g * NC + t] = s;
    }
}

// ---------------- launcher ----------------

extern "C" void kernel_launch(void* const* d_in, const int* in_sizes, int n_in,
                              void* d_out, int out_size, void* d_ws, size_t ws_size,
                              hipStream_t stream) {
    const float* x     = (const float*)d_in[0];
    const int*   ei    = (const int*)d_in[1];
    const int*   batch = (const int*)d_in[2];
    const float* Wl    = (const float*)d_in[3];
    const float* bl    = (const float*)d_in[4];
    const float* Wr    = (const float*)d_in[5];
    const float* gamma = (const float*)d_in[6];
    const float* beta  = (const float*)d_in[7];
    const float* Wc    = (const float*)d_in[8];
    const float* bc    = (const float*)d_in[9];
    float* outp = (float*)d_out;

    char* p = (char*)d_ws;
    auto alloc = [&](size_t bytes) { char* r = p; p += (bytes + 255) & ~(size_t)255; return r; };
    float* bufA    = (float*)alloc((size_t)NN * DD * 4);
    float* bufB    = (float*)alloc((size_t)NN * DD * 4);
    float* deg_inv = (float*)alloc((size_t)NN * 4);
    int*   csr_off = (int*)alloc((size_t)(NN + 1) * 4);
    int*   csr_cur = (int*)alloc((size_t)NN * 4);
    int*   esrc    = (int*)alloc((size_t)NE * 4);
    int*   part    = (int*)alloc(1024 * 4);
    float* bn      = (float*)alloc(2 * DD * 4);
    float* ss      = (float*)alloc(2 * DD * 4);
    float* pool    = (float*)alloc((size_t)NG * DD * 4);
    int*   pcnt    = (int*)alloc((size_t)NG * 4);

    hipMemsetAsync(csr_cur, 0, (size_t)NN * 4, stream);
    hipMemsetAsync(pool, 0, (size_t)NG * DD * 4, stream);

    k_hist<<<NE / 256, 256, 0, stream>>>(ei, csr_cur);
    k_scan_part<<<NB_SCAN, 256, 0, stream>>>(csr_cur, part);
    k_scan_top<<<1, 128, 0, stream>>>(part, NB_SCAN);
    k_scan_final<<<NB_SCAN, 256, 0, stream>>>(part, csr_cur, csr_off, deg_inv);
    k_fill<<<NE / 256, 256, 0, stream>>>(ei, csr_cur, esrc);

    for (int l = 0; l < NL; l++) {
        float* dst = (l == 0) ? bufA : ((l == 1) ? bufB : bufA);
        const float* hin = (l == 0) ? x : ((l == 1) ? bufA : bufB);
        hipMemsetAsync(bn, 0, 2 * DD * 4, stream);
        k_agg<<<NN, 128, 0, stream>>>(hin, csr_off, esrc, deg_inv, dst);
        k_gemm<<<NN / TM, 256, 0, stream>>>(dst, hin, Wl + (size_t)l * DD * DD, bl + (size_t)l * DD,
                                            Wr + (size_t)l * DD * DD, dst, bn);
        k_bnfinal<<<1, 128, 0, stream>>>(bn, gamma + (size_t)l * DD, beta + (size_t)l * DD, ss);
        k_bnrelu<<<NN * DD / 4 / 256, 256, 0, stream>>>(dst, ss);
    }

    k_pool<<<NG * 4, 128, 0, stream>>>(bufA, batch, pool, pcnt);
    k_cls<<<NG, 128, 0, stream>>>(pool, pcnt, Wc, bc, outp);
}

// Round 8
// 797.159 us; speedup vs baseline: 1.2933x; 1.2933x over previous
//
#include <hip/hip_runtime.h>

#define NN 100000      // nodes
#define NE 800000      // edges
#define DD 128         // hidden dim
#define NL 3           // layers
#define NC 10          // classes
#define NG 64          // graphs
#define EPSV 1e-5f
#define SCAN_CHUNK 1024
#define NB_SCAN ((NN + SCAN_CHUNK - 1) / SCAN_CHUNK)   // 98

typedef short s8v __attribute__((ext_vector_type(8)));   // 8 bf16 (4 VGPRs)
typedef float f4v __attribute__((ext_vector_type(4)));   // mfma accumulator

// ---- bf16 pack/unpack helpers (RNE) ----
__device__ inline unsigned int pack_bf2(float a, float b) {
    unsigned int ua = __float_as_uint(a); ua += 0x7fffu + ((ua >> 16) & 1u);
    unsigned int ub = __float_as_uint(b); ub += 0x7fffu + ((ub >> 16) & 1u);
    return (ua >> 16) | (ub & 0xffff0000u);
}
__device__ inline float2 unpack_bf2(unsigned int v) {
    return make_float2(__uint_as_float(v << 16), __uint_as_float(v & 0xffff0000u));
}

// ---------------- CSR build ----------------

__global__ void k_hist(const int* __restrict__ ei, int* __restrict__ cnt) {
    int e = blockIdx.x * 256 + threadIdx.x;
    if (e < NE) atomicAdd(&cnt[ei[NE + e]], 1);
}

__global__ void k_scan_part(const int* __restrict__ cnt, int* __restrict__ part) {
    __shared__ int lds[256];
    int base = blockIdx.x * SCAN_CHUNK + threadIdx.x * 4;
    int s = 0;
    for (int i = 0; i < 4; i++) { int idx = base + i; if (idx < NN) s += cnt[idx]; }
    lds[threadIdx.x] = s; __syncthreads();
    for (int off = 128; off > 0; off >>= 1) {
        if (threadIdx.x < off) lds[threadIdx.x] += lds[threadIdx.x + off];
        __syncthreads();
    }
    if (threadIdx.x == 0) part[blockIdx.x] = lds[0];
}

__global__ void k_scan_top(int* part, int nb) {
    __shared__ int lds[128];
    int t = threadIdx.x;
    int v = (t < nb) ? part[t] : 0;
    lds[t] = v; __syncthreads();
    for (int off = 1; off < 128; off <<= 1) {
        int add = (t >= off) ? lds[t - off] : 0;
        __syncthreads();
        lds[t] += add;
        __syncthreads();
    }
    if (t < nb) part[t] = lds[t] - v;   // exclusive
}

__global__ void k_scan_final(const int* __restrict__ part, int* __restrict__ cnt,
                             int* __restrict__ offs, float* __restrict__ deg_inv) {
    __shared__ int lds[256];
    int t = threadIdx.x;
    int base = blockIdx.x * SCAN_CHUNK + t * 4;
    int v[4]; int s = 0;
    for (int i = 0; i < 4; i++) { int idx = base + i; v[i] = (idx < NN) ? cnt[idx] : 0; s += v[i]; }
    lds[t] = s; __syncthreads();
    for (int o = 1; o < 256; o <<= 1) {
        int add = (t >= o) ? lds[t - o] : 0;
        __syncthreads();
        lds[t] += add;
        __syncthreads();
    }
    int excl = lds[t] - s + part[blockIdx.x];
    for (int i = 0; i < 4; i++) {
        int idx = base + i;
        if (idx < NN) {
            offs[idx] = excl;
            cnt[idx]  = excl;   // becomes the fill cursor
            deg_inv[idx] = 1.0f / (float)max(v[i], 1);
            excl += v[i];
        }
    }
    if (blockIdx.x == 0 && t == 0) offs[NN] = NE;
}

__global__ void k_fill(const int* __restrict__ ei, int* __restrict__ cur, int* __restrict__ esrc) {
    int e = blockIdx.x * 256 + threadIdx.x;
    if (e < NE) {
        int d = ei[NE + e];
        int slot = atomicAdd(&cur[d], 1);
        esrc[slot] = ei[e];
    }
}

// ---------------- x -> bf16 cast ----------------

__global__ __launch_bounds__(256) void k_cast(const float* __restrict__ x, unsigned int* __restrict__ o) {
    size_t i = (size_t)blockIdx.x * 256 + threadIdx.x;   // u32 index, NN*64 total
    float2 v = ((const float2*)x)[i];
    o[i] = pack_bf2(v.x, v.y);
}

// ---------------- weight transpose+convert: W[k][f] f32 -> WT[f][kpair] bf16x2 ----------------

__global__ __launch_bounds__(256) void k_transW(const float* __restrict__ Wl, const float* __restrict__ Wr,
                                                unsigned int* __restrict__ WT) {
    int m = blockIdx.x;                       // 0..5: layer = m>>1, which = m&1
    const float* W = ((m & 1) ? Wr : Wl) + (size_t)(m >> 1) * DD * DD;
    unsigned int* o = WT + (size_t)m * DD * 64;
    for (int idx = threadIdx.x; idx < DD * 64; idx += 256) {
        int f = idx >> 6, kp = idx & 63;
        float w0 = W[(size_t)(2 * kp) * DD + f];
        float w1 = W[(size_t)(2 * kp + 1) * DD + f];
        o[idx] = pack_bf2(w0, w1);
    }
}

// ---------------- aggregation (bf16): one wave per node, 2 feats/lane ----------------

__global__ __launch_bounds__(64) void k_agg(const unsigned int* __restrict__ hb,
                                            const int* __restrict__ offs,
                                            const int* __restrict__ esrc,
                                            const float* __restrict__ deg_inv,
                                            unsigned int* __restrict__ outb) {
    int n = blockIdx.x;
    int t = threadIdx.x;
    int s0 = offs[n], s1 = offs[n + 1];
    float ax = 0.f, ay = 0.f;
    int j = s0;
    for (; j + 1 < s1; j += 2) {
        unsigned int v0 = hb[(size_t)esrc[j] * 64 + t];
        unsigned int v1 = hb[(size_t)esrc[j + 1] * 64 + t];
        float2 f0 = unpack_bf2(v0), f1 = unpack_bf2(v1);
        ax += f0.x + f1.x; ay += f0.y + f1.y;
    }
    if (j < s1) {
        float2 f0 = unpack_bf2(hb[(size_t)esrc[j] * 64 + t]);
        ax += f0.x; ay += f0.y;
    }
    float di = deg_inv[n];
    outb[(size_t)n * 64 + t] = pack_bf2(ax * di, ay * di);
}

// ---------------- MFMA GEMM: out = agg@Wl + bl + h@Wr (f32 out) + BN partials ----------------
// block = 128 thr (2 waves); wave wv covers cols [wv*64, wv*64+64); 32 nodes/block.
// No LDS: A/B fragments loaded straight from global (bf16), f32 accumulate.

__global__ __launch_bounds__(128) void k_gemm_mfma(
    const unsigned short* __restrict__ aggb, const unsigned short* __restrict__ hb,
    const unsigned short* __restrict__ WlT, const unsigned short* __restrict__ WrT,  // [128 f][128 k] bf16
    const float* __restrict__ bl,
    float* __restrict__ outp, float* __restrict__ bn /* [2][DD] */) {

    int n0 = blockIdx.x * 32;
    int wv = threadIdx.x >> 6;         // 0..1 : column half
    int l  = threadIdx.x & 63;
    int r  = l & 15;                   // row (A) / col (B,D) within fragment
    int q  = l >> 4;                   // k-chunk quad (in), row-quad (out)
    int c0 = wv * 64;

    f4v acc[2][4];
    #pragma unroll
    for (int i = 0; i < 2; i++)
        #pragma unroll
        for (int j = 0; j < 4; j++)
            acc[i][j] = (f4v){0.f, 0.f, 0.f, 0.f};

    #pragma unroll
    for (int ks = 0; ks < 4; ++ks) {
        int kb = ks * 32 + q * 8;      // element offset along k
        s8v a0 = *(const s8v*)(aggb + (size_t)(n0 + r) * DD + kb);
        s8v a1 = *(const s8v*)(aggb + (size_t)(n0 + 16 + r) * DD + kb);
        s8v h0 = *(const s8v*)(hb   + (size_t)(n0 + r) * DD + kb);
        s8v h1 = *(const s8v*)(hb   + (size_t)(n0 + 16 + r) * DD + kb);
        #pragma unroll
        for (int cf = 0; cf < 4; ++cf) {
            int col = c0 + cf * 16 + r;
            s8v wl = *(const s8v*)(WlT + (size_t)col * DD + kb);
            s8v wr = *(const s8v*)(WrT + (size_t)col * DD + kb);
            acc[0][cf] = __builtin_amdgcn_mfma_f32_16x16x32_bf16(a0, wl, acc[0][cf], 0, 0, 0);
            acc[0][cf] = __builtin_amdgcn_mfma_f32_16x16x32_bf16(h0, wr, acc[0][cf], 0, 0, 0);
            acc[1][cf] = __builtin_amdgcn_mfma_f32_16x16x32_bf16(a1, wl, acc[1][cf], 0, 0, 0);
            acc[1][cf] = __builtin_amdgcn_mfma_f32_16x16x32_bf16(h1, wr, acc[1][cf], 0, 0, 0);
        }
    }

    // epilogue: bias, store f32, BN partial sums (reduce across q via shfl)
    #pragma unroll
    for (int cf = 0; cf < 4; ++cf) {
        int col = c0 + cf * 16 + r;
        float b = bl[col];
        float s = 0.f, ss = 0.f;
        #pragma unroll
        for (int rf = 0; rf < 2; ++rf) {
            #pragma unroll
            for (int j = 0; j < 4; ++j) {
                float v = acc[rf][cf][j] + b;
                int n = n0 + rf * 16 + q * 4 + j;
                outp[(size_t)n * DD + col] = v;
                s += v; ss += v * v;
            }
        }
        s  += __shfl_xor(s, 16);  s  += __shfl_xor(s, 32);
        ss += __shfl_xor(ss, 16); ss += __shfl_xor(ss, 32);
        if (q == 0) {
            atomicAdd(&bn[col], s);
            atomicAdd(&bn[DD + col], ss);
        }
    }
}

// ---------------- BN finalize + apply(+ReLU) -> bf16 ----------------

__global__ void k_bnfinal(const float* __restrict__ bn, const float* __restrict__ gamma,
                          const float* __restrict__ beta, float* __restrict__ ss) {
    int f = threadIdx.x;
    float mu = bn[f] / (float)NN;
    float var = bn[DD + f] / (float)NN - mu * mu;
    var = fmaxf(var, 0.f);
    float sc = gamma[f] * rsqrtf(var + EPSV);
    ss[f] = sc;
    ss[DD + f] = beta[f] - mu * sc;
}

__global__ __launch_bounds__(256) void k_bnrelu(const float* __restrict__ gout,
                                                const float* __restrict__ ss,
                                                unsigned int* __restrict__ hb) {
    size_t i = (size_t)blockIdx.x * 256 + threadIdx.x;   // u32 index, NN*64 total
    int fp = (int)(i & 63);                              // feature pair
    float2 v  = ((const float2*)gout)[i];
    float2 sc = ((const float2*)ss)[fp];
    float2 sh = ((const float2*)(ss + DD))[fp];
    float a = fmaxf(v.x * sc.x + sh.x, 0.f);
    float b = fmaxf(v.y * sc.y + sh.y, 0.f);
    hb[i] = pack_bf2(a, b);
}

// ---------------- pooling + classifier ----------------

__device__ int lbound(const int* __restrict__ a, int v) {
    int lo = 0, hi = NN;
    while (lo < hi) { int m = (lo + hi) >> 1; if (a[m] < v) lo = m + 1; else hi = m; }
    return lo;
}

__global__ __launch_bounds__(64) void k_pool(const unsigned int* __restrict__ hb,
                                             const int* __restrict__ batch,
                                             float* __restrict__ pool, int* __restrict__ pcnt) {
    int g = blockIdx.x >> 2;
    int c = blockIdx.x & 3;
    int s = lbound(batch, g);
    int e = lbound(batch, g + 1);
    int len = e - s;
    int s2 = s + (int)(((long long)len * c) >> 2);
    int e2 = s + (int)(((long long)len * (c + 1)) >> 2);
    int t = threadIdx.x;
    float ax = 0.f, ay = 0.f;
    for (int n = s2; n < e2; ++n) {
        float2 f = unpack_bf2(hb[(size_t)n * 64 + t]);
        ax += f.x; ay += f.y;
    }
    atomicAdd(&pool[g * DD + 2 * t], ax);
    atomicAdd(&pool[g * DD + 2 * t + 1], ay);
    if (t == 0 && c == 0) pcnt[g] = len;
}

__global__ __launch_bounds__(128) void k_cls(const float* __restrict__ pool, const int* __restrict__ pcnt,
                                             const float* __restrict__ Wc, const float* __restrict__ bc,
                                             float* __restrict__ outp) {
    __shared__ float emb[DD];
    int g = blockIdx.x; int t = threadIdx.x;
    float cnt = fmaxf((float)pcnt[g], 1.f);
    emb[t] = pool[g * DD + t] / cnt;
    __syncthreads();
    if (t < NC) {
        float s = bc[t];
        for (int k = 0; k < DD; k++) s += emb[k] * Wc[k * NC + t];
        outp[g * NC + t] = s;
    }
}

// ---------------- launcher ----------------

extern "C" void kernel_launch(void* const* d_in, const int* in_sizes, int n_in,
                              void* d_out, int out_size, void* d_ws, size_t ws_size,
                              hipStream_t stream) {
    const float* x     = (const float*)d_in[0];
    const int*   ei    = (const int*)d_in[1];
    const int*   batch = (const int*)d_in[2];
    const float* Wl    = (const float*)d_in[3];
    const float* bl    = (const float*)d_in[4];
    const float* Wr    = (const float*)d_in[5];
    const float* gamma = (const float*)d_in[6];
    const float* beta  = (const float*)d_in[7];
    const float* Wc    = (const float*)d_in[8];
    const float* bc    = (const float*)d_in[9];
    float* outp = (float*)d_out;

    char* p = (char*)d_ws;
    auto alloc = [&](size_t bytes) { char* r = p; p += (bytes + 255) & ~(size_t)255; return r; };
    unsigned int* bufA = (unsigned int*)alloc((size_t)NN * 64 * 4);   // h (bf16 pairs)
    unsigned int* bufB = (unsigned int*)alloc((size_t)NN * 64 * 4);   // agg scratch (bf16 pairs)
    float* gout    = (float*)alloc((size_t)NN * DD * 4);              // gemm out f32
    unsigned int* WT = (unsigned int*)alloc((size_t)NL * 2 * DD * 64 * 4);
    float* deg_inv = (float*)alloc((size_t)NN * 4);
    int*   csr_off = (int*)alloc((size_t)(NN + 1) * 4);
    int*   csr_cur = (int*)alloc((size_t)NN * 4);
    int*   esrc    = (int*)alloc((size_t)NE * 4);
    int*   part    = (int*)alloc(1024 * 4);
    float* bn      = (float*)alloc(2 * DD * 4);
    float* ss      = (float*)alloc(2 * DD * 4);
    float* pool    = (float*)alloc((size_t)NG * DD * 4);
    int*   pcnt    = (int*)alloc((size_t)NG * 4);

    hipMemsetAsync(csr_cur, 0, (size_t)NN * 4, stream);
    hipMemsetAsync(pool, 0, (size_t)NG * DD * 4, stream);

    k_hist<<<NE / 256, 256, 0, stream>>>(ei, csr_cur);
    k_scan_part<<<NB_SCAN, 256, 0, stream>>>(csr_cur, part);
    k_scan_top<<<1, 128, 0, stream>>>(part, NB_SCAN);
    k_scan_final<<<NB_SCAN, 256, 0, stream>>>(part, csr_cur, csr_off, deg_inv);
    k_fill<<<NE / 256, 256, 0, stream>>>(ei, csr_cur, esrc);

    k_cast<<<NN * 64 / 256, 256, 0, stream>>>(x, bufA);
    k_transW<<<NL * 2, 256, 0, stream>>>(Wl, Wr, WT);

    for (int l = 0; l < NL; l++) {
        hipMemsetAsync(bn, 0, 2 * DD * 4, stream);
        k_agg<<<NN, 64, 0, stream>>>(bufA, csr_off, esrc, deg_inv, bufB);
        const unsigned short* WlT = (const unsigned short*)(WT + (size_t)(2 * l) * DD * 64);
        const unsigned short* WrT = (const unsigned short*)(WT + (size_t)(2 * l + 1) * DD * 64);
        k_gemm_mfma<<<NN / 32, 128, 0, stream>>>((const unsigned short*)bufB, (const unsigned short*)bufA,
                                                 WlT, WrT, bl + (size_t)l * DD, gout, bn);
        k_bnfinal<<<1, 128, 0, stream>>>(bn, gamma + (size_t)l * DD, beta + (size_t)l * DD, ss);
        k_bnrelu<<<NN * 64 / 256, 256, 0, stream>>>(gout, ss, bufA);
    }

    k_pool<<<NG * 4, 64, 0, stream>>>(bufA, batch, pool, pcnt);
    k_cls<<<NG, 128, 0, stream>>>(pool, pcnt, Wc, bc, outp);
}

// Round 9
// 738.708 us; speedup vs baseline: 1.3957x; 1.0791x over previous
//
#include <hip/hip_runtime.h>

#define NN 100000      // nodes
#define NE 800000      // edges
#define DD 128         // hidden dim
#define NL 3           // layers
#define NC 10          // classes
#define NG 64          // graphs
#define EPSV 1e-5f
#define SCAN_CHUNK 1024
#define NB_SCAN ((NN + SCAN_CHUNK - 1) / SCAN_CHUNK)   // 98
#define PB 2048        // pooling waves

typedef short s8v __attribute__((ext_vector_type(8)));   // 8 bf16 (4 VGPRs)
typedef float f4v __attribute__((ext_vector_type(4)));   // mfma accumulator

// ---- bf16 pack/unpack helpers (RNE) ----
__device__ inline unsigned int pack_bf2(float a, float b) {
    unsigned int ua = __float_as_uint(a); ua += 0x7fffu + ((ua >> 16) & 1u);
    unsigned int ub = __float_as_uint(b); ub += 0x7fffu + ((ub >> 16) & 1u);
    return (ua >> 16) | (ub & 0xffff0000u);
}
__device__ inline float2 unpack_bf2(unsigned int v) {
    return make_float2(__uint_as_float(v << 16), __uint_as_float(v & 0xffff0000u));
}

// ---------------- CSR build ----------------

__global__ void k_hist(const int* __restrict__ ei, int* __restrict__ cnt) {
    int e = blockIdx.x * 256 + threadIdx.x;
    if (e < NE) atomicAdd(&cnt[ei[NE + e]], 1);
}

__global__ void k_scan_part(const int* __restrict__ cnt, int* __restrict__ part) {
    __shared__ int lds[256];
    int base = blockIdx.x * SCAN_CHUNK + threadIdx.x * 4;
    int s = 0;
    for (int i = 0; i < 4; i++) { int idx = base + i; if (idx < NN) s += cnt[idx]; }
    lds[threadIdx.x] = s; __syncthreads();
    for (int off = 128; off > 0; off >>= 1) {
        if (threadIdx.x < off) lds[threadIdx.x] += lds[threadIdx.x + off];
        __syncthreads();
    }
    if (threadIdx.x == 0) part[blockIdx.x] = lds[0];
}

__global__ void k_scan_top(int* part, int nb) {
    __shared__ int lds[128];
    int t = threadIdx.x;
    int v = (t < nb) ? part[t] : 0;
    lds[t] = v; __syncthreads();
    for (int off = 1; off < 128; off <<= 1) {
        int add = (t >= off) ? lds[t - off] : 0;
        __syncthreads();
        lds[t] += add;
        __syncthreads();
    }
    if (t < nb) part[t] = lds[t] - v;   // exclusive
}

__global__ void k_scan_final(const int* __restrict__ part, int* __restrict__ cnt,
                             int* __restrict__ offs, float* __restrict__ deg_inv) {
    __shared__ int lds[256];
    int t = threadIdx.x;
    int base = blockIdx.x * SCAN_CHUNK + t * 4;
    int v[4]; int s = 0;
    for (int i = 0; i < 4; i++) { int idx = base + i; v[i] = (idx < NN) ? cnt[idx] : 0; s += v[i]; }
    lds[t] = s; __syncthreads();
    for (int o = 1; o < 256; o <<= 1) {
        int add = (t >= o) ? lds[t - o] : 0;
        __syncthreads();
        lds[t] += add;
        __syncthreads();
    }
    int excl = lds[t] - s + part[blockIdx.x];
    for (int i = 0; i < 4; i++) {
        int idx = base + i;
        if (idx < NN) {
            offs[idx] = excl;
            cnt[idx]  = excl;   // becomes the fill cursor
            deg_inv[idx] = 1.0f / (float)max(v[i], 1);
            excl += v[i];
        }
    }
    if (blockIdx.x == 0 && t == 0) offs[NN] = NE;
}

__global__ void k_fill(const int* __restrict__ ei, int* __restrict__ cur, int* __restrict__ esrc) {
    int e = blockIdx.x * 256 + threadIdx.x;
    if (e < NE) {
        int d = ei[NE + e];
        int slot = atomicAdd(&cur[d], 1);
        esrc[slot] = ei[e];
    }
}

// ---------------- x -> bf16 cast ----------------

__global__ __launch_bounds__(256) void k_cast(const float* __restrict__ x, unsigned int* __restrict__ o) {
    size_t i = (size_t)blockIdx.x * 256 + threadIdx.x;   // u32 index, NN*64 total
    float2 v = ((const float2*)x)[i];
    o[i] = pack_bf2(v.x, v.y);
}

// ---------------- weight transpose+convert: W[k][f] f32 -> WT[f][kpair] bf16x2 ----------------

__global__ __launch_bounds__(256) void k_transW(const float* __restrict__ Wl, const float* __restrict__ Wr,
                                                unsigned int* __restrict__ WT) {
    int m = blockIdx.x;                       // 0..5: layer = m>>1, which = m&1
    const float* W = ((m & 1) ? Wr : Wl) + (size_t)(m >> 1) * DD * DD;
    unsigned int* o = WT + (size_t)m * DD * 64;
    for (int idx = threadIdx.x; idx < DD * 64; idx += 256) {
        int f = idx >> 6, kp = idx & 63;
        float w0 = W[(size_t)(2 * kp) * DD + f];
        float w1 = W[(size_t)(2 * kp + 1) * DD + f];
        o[idx] = pack_bf2(w0, w1);
    }
}

// ---------------- aggregation (bf16): one wave per node, 4 nodes/block, unroll 4 ----------------

__global__ __launch_bounds__(256) void k_agg(const unsigned int* __restrict__ hb,
                                             const int* __restrict__ offs,
                                             const int* __restrict__ esrc,
                                             const float* __restrict__ deg_inv,
                                             unsigned int* __restrict__ outb) {
    int n = blockIdx.x * 4 + (threadIdx.x >> 6);
    int t = threadIdx.x & 63;
    int s0 = offs[n], s1 = offs[n + 1];
    float ax = 0.f, ay = 0.f;
    int j = s0;
    for (; j + 3 < s1; j += 4) {
        int e0 = esrc[j], e1 = esrc[j + 1], e2 = esrc[j + 2], e3 = esrc[j + 3];
        unsigned int v0 = hb[(size_t)e0 * 64 + t];
        unsigned int v1 = hb[(size_t)e1 * 64 + t];
        unsigned int v2 = hb[(size_t)e2 * 64 + t];
        unsigned int v3 = hb[(size_t)e3 * 64 + t];
        float2 f0 = unpack_bf2(v0), f1 = unpack_bf2(v1);
        float2 f2 = unpack_bf2(v2), f3 = unpack_bf2(v3);
        ax += (f0.x + f1.x) + (f2.x + f3.x);
        ay += (f0.y + f1.y) + (f2.y + f3.y);
    }
    for (; j < s1; ++j) {
        float2 f0 = unpack_bf2(hb[(size_t)esrc[j] * 64 + t]);
        ax += f0.x; ay += f0.y;
    }
    float di = deg_inv[n];
    outb[(size_t)n * 64 + t] = pack_bf2(ax * di, ay * di);
}

// ---------------- MFMA GEMM: out = agg@Wl + bl + h@Wr (f32 out) + BN partials ----------------
// block = 128 thr (2 waves); wave wv covers cols [wv*64, wv*64+64); 32 nodes/block.
// No LDS: A/B fragments loaded straight from global (bf16), f32 accumulate.

__global__ __launch_bounds__(128) void k_gemm_mfma(
    const unsigned short* __restrict__ aggb, const unsigned short* __restrict__ hb,
    const unsigned short* __restrict__ WlT, const unsigned short* __restrict__ WrT,  // [128 f][128 k] bf16
    const float* __restrict__ bl,
    float* __restrict__ outp, float* __restrict__ bn /* [2][DD] */) {

    int n0 = blockIdx.x * 32;
    int wv = threadIdx.x >> 6;         // 0..1 : column half
    int l  = threadIdx.x & 63;
    int r  = l & 15;                   // row (A) / col (B,D) within fragment
    int q  = l >> 4;                   // k-chunk quad (in), row-quad (out)
    int c0 = wv * 64;

    f4v acc[2][4];
    #pragma unroll
    for (int i = 0; i < 2; i++)
        #pragma unroll
        for (int j = 0; j < 4; j++)
            acc[i][j] = (f4v){0.f, 0.f, 0.f, 0.f};

    #pragma unroll
    for (int ks = 0; ks < 4; ++ks) {
        int kb = ks * 32 + q * 8;      // element offset along k
        s8v a0 = *(const s8v*)(aggb + (size_t)(n0 + r) * DD + kb);
        s8v a1 = *(const s8v*)(aggb + (size_t)(n0 + 16 + r) * DD + kb);
        s8v h0 = *(const s8v*)(hb   + (size_t)(n0 + r) * DD + kb);
        s8v h1 = *(const s8v*)(hb   + (size_t)(n0 + 16 + r) * DD + kb);
        #pragma unroll
        for (int cf = 0; cf < 4; ++cf) {
            int col = c0 + cf * 16 + r;
            s8v wl = *(const s8v*)(WlT + (size_t)col * DD + kb);
            s8v wr = *(const s8v*)(WrT + (size_t)col * DD + kb);
            acc[0][cf] = __builtin_amdgcn_mfma_f32_16x16x32_bf16(a0, wl, acc[0][cf], 0, 0, 0);
            acc[0][cf] = __builtin_amdgcn_mfma_f32_16x16x32_bf16(h0, wr, acc[0][cf], 0, 0, 0);
            acc[1][cf] = __builtin_amdgcn_mfma_f32_16x16x32_bf16(a1, wl, acc[1][cf], 0, 0, 0);
            acc[1][cf] = __builtin_amdgcn_mfma_f32_16x16x32_bf16(h1, wr, acc[1][cf], 0, 0, 0);
        }
    }

    // epilogue: bias, store f32, BN partial sums (reduce across q via shfl)
    #pragma unroll
    for (int cf = 0; cf < 4; ++cf) {
        int col = c0 + cf * 16 + r;
        float b = bl[col];
        float s = 0.f, ss = 0.f;
        #pragma unroll
        for (int rf = 0; rf < 2; ++rf) {
            #pragma unroll
            for (int j = 0; j < 4; ++j) {
                float v = acc[rf][cf][j] + b;
                int n = n0 + rf * 16 + q * 4 + j;
                outp[(size_t)n * DD + col] = v;
                s += v; ss += v * v;
            }
        }
        s  += __shfl_xor(s, 16);  s  += __shfl_xor(s, 32);
        ss += __shfl_xor(ss, 16); ss += __shfl_xor(ss, 32);
        if (q == 0) {
            atomicAdd(&bn[col], s);
            atomicAdd(&bn[DD + col], ss);
        }
    }
}

// ---------------- BN finalize + apply(+ReLU) -> bf16 ----------------

__global__ void k_bnfinal(const float* __restrict__ bn, const float* __restrict__ gamma,
                          const float* __restrict__ beta, float* __restrict__ ss) {
    int f = threadIdx.x;
    float mu = bn[f] / (float)NN;
    float var = bn[DD + f] / (float)NN - mu * mu;
    var = fmaxf(var, 0.f);
    float sc = gamma[f] * rsqrtf(var + EPSV);
    ss[f] = sc;
    ss[DD + f] = beta[f] - mu * sc;
}

__global__ __launch_bounds__(256) void k_bnrelu(const float* __restrict__ gout,
                                                const float* __restrict__ ss,
                                                unsigned int* __restrict__ hb) {
    size_t i = (size_t)blockIdx.x * 256 + threadIdx.x;   // u32 index, NN*64 total
    int fp = (int)(i & 63);                              // feature pair
    float2 v  = ((const float2*)gout)[i];
    float2 sc = ((const float2*)ss)[fp];
    float2 sh = ((const float2*)(ss + DD))[fp];
    float a = fmaxf(v.x * sc.x + sh.x, 0.f);
    float b = fmaxf(v.y * sc.y + sh.y, 0.f);
    hb[i] = pack_bf2(a, b);
}

// ---------------- pooling: wave-per-slab over sorted batch, flush on graph change ----------------

__global__ __launch_bounds__(64) void k_pool(const unsigned int* __restrict__ hb,
                                             const int* __restrict__ batch,
                                             float* __restrict__ pool) {
    const int chunk = (NN + PB - 1) / PB;   // 49
    int start = blockIdx.x * chunk;
    if (start >= NN) return;
    int end = min(start + chunk, NN);
    int t = threadIdx.x;
    int cur = batch[start];
    float ax = 0.f, ay = 0.f;
    for (int n = start; n < end; ++n) {
        int g = batch[n];
        if (g != cur) {
            atomicAdd(&pool[cur * DD + 2 * t], ax);
            atomicAdd(&pool[cur * DD + 2 * t + 1], ay);
            ax = 0.f; ay = 0.f; cur = g;
        }
        float2 f = unpack_bf2(hb[(size_t)n * 64 + t]);
        ax += f.x; ay += f.y;
    }
    atomicAdd(&pool[cur * DD + 2 * t], ax);
    atomicAdd(&pool[cur * DD + 2 * t + 1], ay);
}

// ---------------- classifier ----------------

__device__ int lbound(const int* __restrict__ a, int v) {
    int lo = 0, hi = NN;
    while (lo < hi) { int m = (lo + hi) >> 1; if (a[m] < v) lo = m + 1; else hi = m; }
    return lo;
}

__global__ __launch_bounds__(128) void k_cls(const float* __restrict__ pool, const int* __restrict__ batch,
                                             const float* __restrict__ Wc, const float* __restrict__ bc,
                                             float* __restrict__ outp) {
    __shared__ float emb[DD];
    int g = blockIdx.x; int t = threadIdx.x;
    int s0 = lbound(batch, g);
    int e0 = lbound(batch, g + 1);
    float cnt = fmaxf((float)(e0 - s0), 1.f);
    emb[t] = pool[g * DD + t] / cnt;
    __syncthreads();
    if (t < NC) {
        float s = bc[t];
        for (int k = 0; k < DD; k++) s += emb[k] * Wc[k * NC + t];
        outp[g * NC + t] = s;
    }
}

// ---------------- launcher ----------------

extern "C" void kernel_launch(void* const* d_in, const int* in_sizes, int n_in,
                              void* d_out, int out_size, void* d_ws, size_t ws_size,
                              hipStream_t stream) {
    const float* x     = (const float*)d_in[0];
    const int*   ei    = (const int*)d_in[1];
    const int*   batch = (const int*)d_in[2];
    const float* Wl    = (const float*)d_in[3];
    const float* bl    = (const float*)d_in[4];
    const float* Wr    = (const float*)d_in[5];
    const float* gamma = (const float*)d_in[6];
    const float* beta  = (const float*)d_in[7];
    const float* Wc    = (const float*)d_in[8];
    const float* bc    = (const float*)d_in[9];
    float* outp = (float*)d_out;

    char* p = (char*)d_ws;
    auto alloc = [&](size_t bytes) { char* r = p; p += (bytes + 255) & ~(size_t)255; return r; };
    unsigned int* bufA = (unsigned int*)alloc((size_t)NN * 64 * 4);   // h (bf16 pairs)
    unsigned int* bufB = (unsigned int*)alloc((size_t)NN * 64 * 4);   // agg scratch (bf16 pairs)
    float* gout    = (float*)alloc((size_t)NN * DD * 4);              // gemm out f32
    unsigned int* WT = (unsigned int*)alloc((size_t)NL * 2 * DD * 64 * 4);
    float* deg_inv = (float*)alloc((size_t)NN * 4);
    int*   csr_off = (int*)alloc((size_t)(NN + 1) * 4);
    int*   csr_cur = (int*)alloc((size_t)NN * 4);
    int*   esrc    = (int*)alloc((size_t)NE * 4);
    int*   part    = (int*)alloc(1024 * 4);
    float* bn      = (float*)alloc(2 * DD * 4);
    float* ss      = (float*)alloc(2 * DD * 4);
    float* pool    = (float*)alloc((size_t)NG * DD * 4);

    hipMemsetAsync(csr_cur, 0, (size_t)NN * 4, stream);
    hipMemsetAsync(pool, 0, (size_t)NG * DD * 4, stream);

    k_hist<<<NE / 256, 256, 0, stream>>>(ei, csr_cur);
    k_scan_part<<<NB_SCAN, 256, 0, stream>>>(csr_cur, part);
    k_scan_top<<<1, 128, 0, stream>>>(part, NB_SCAN);
    k_scan_final<<<NB_SCAN, 256, 0, stream>>>(part, csr_cur, csr_off, deg_inv);
    k_fill<<<NE / 256, 256, 0, stream>>>(ei, csr_cur, esrc);

    k_cast<<<NN * 64 / 256, 256, 0, stream>>>(x, bufA);
    k_transW<<<NL * 2, 256, 0, stream>>>(Wl, Wr, WT);

    for (int l = 0; l < NL; l++) {
        hipMemsetAsync(bn, 0, 2 * DD * 4, stream);
        k_agg<<<NN / 4, 256, 0, stream>>>(bufA, csr_off, esrc, deg_inv, bufB);
        const unsigned short* WlT = (const unsigned short*)(WT + (size_t)(2 * l) * DD * 64);
        const unsigned short* WrT = (const unsigned short*)(WT + (size_t)(2 * l + 1) * DD * 64);
        k_gemm_mfma<<<NN / 32, 128, 0, stream>>>((const unsigned short*)bufB, (const unsigned short*)bufA,
                                                 WlT, WrT, bl + (size_t)l * DD, gout, bn);
        k_bnfinal<<<1, 128, 0, stream>>>(bn, gamma + (size_t)l * DD, beta + (size_t)l * DD, ss);
        k_bnrelu<<<NN * 64 / 256, 256, 0, stream>>>(gout, ss, bufA);
    }

    k_pool<<<PB, 64, 0, stream>>>(bufA, batch, pool);
    k_cls<<<NG, 128, 0, stream>>>(pool, batch, Wc, bc, outp);
}

// Round 11
// 591.311 us; speedup vs baseline: 1.7436x; 1.2493x over previous
//
#include <hip/hip_runtime.h>

#define NN 100000      // nodes
#define NE 800000      // edges
#define DD 128         // hidden dim
#define NL 3           // layers
#define NC 10          // classes
#define NG 64          // graphs
#define EPSV 1e-5f
#define SCAN_CHUNK 1024
#define NB_SCAN ((NN + SCAN_CHUNK - 1) / SCAN_CHUNK)   // 98
#define PB 2048        // pooling waves
#define NSTRIP (NN / 16)   // 6250 16-node strips
#define GEMM_BLOCKS 512
#define GEMM_WAVES (GEMM_BLOCKS * 4)

typedef short s8v __attribute__((ext_vector_type(8)));   // 8 bf16 (4 VGPRs)
typedef float f4v __attribute__((ext_vector_type(4)));   // mfma accumulator

// ---- bf16 pack/unpack helpers (RNE) ----
__device__ inline unsigned int pack_bf2(float a, float b) {
    unsigned int ua = __float_as_uint(a); ua += 0x7fffu + ((ua >> 16) & 1u);
    unsigned int ub = __float_as_uint(b); ub += 0x7fffu + ((ub >> 16) & 1u);
    return (ua >> 16) | (ub & 0xffff0000u);
}
__device__ inline float2 unpack_bf2(unsigned int v) {
    return make_float2(__uint_as_float(v << 16), __uint_as_float(v & 0xffff0000u));
}

// ---------------- CSR build ----------------

__global__ void k_hist(const int* __restrict__ ei, int* __restrict__ cnt) {
    int e = blockIdx.x * 256 + threadIdx.x;
    if (e < NE) atomicAdd(&cnt[ei[NE + e]], 1);
}

__global__ void k_scan_part(const int* __restrict__ cnt, int* __restrict__ part) {
    __shared__ int lds[256];
    int base = blockIdx.x * SCAN_CHUNK + threadIdx.x * 4;
    int s = 0;
    for (int i = 0; i < 4; i++) { int idx = base + i; if (idx < NN) s += cnt[idx]; }
    lds[threadIdx.x] = s; __syncthreads();
    for (int off = 128; off > 0; off >>= 1) {
        if (threadIdx.x < off) lds[threadIdx.x] += lds[threadIdx.x + off];
        __syncthreads();
    }
    if (threadIdx.x == 0) part[blockIdx.x] = lds[0];
}

__global__ void k_scan_top(int* part, int nb) {
    __shared__ int lds[128];
    int t = threadIdx.x;
    int v = (t < nb) ? part[t] : 0;
    lds[t] = v; __syncthreads();
    for (int off = 1; off < 128; off <<= 1) {
        int add = (t >= off) ? lds[t - off] : 0;
        __syncthreads();
        lds[t] += add;
        __syncthreads();
    }
    if (t < nb) part[t] = lds[t] - v;   // exclusive
}

__global__ void k_scan_final(const int* __restrict__ part, int* __restrict__ cnt,
                             int* __restrict__ offs, float* __restrict__ deg_inv) {
    __shared__ int lds[256];
    int t = threadIdx.x;
    int base = blockIdx.x * SCAN_CHUNK + t * 4;
    int v[4]; int s = 0;
    for (int i = 0; i < 4; i++) { int idx = base + i; v[i] = (idx < NN) ? cnt[idx] : 0; s += v[i]; }
    lds[t] = s; __syncthreads();
    for (int o = 1; o < 256; o <<= 1) {
        int add = (t >= o) ? lds[t - o] : 0;
        __syncthreads();
        lds[t] += add;
        __syncthreads();
    }
    int excl = lds[t] - s + part[blockIdx.x];
    for (int i = 0; i < 4; i++) {
        int idx = base + i;
        if (idx < NN) {
            offs[idx] = excl;
            cnt[idx]  = excl;   // becomes the fill cursor
            deg_inv[idx] = 1.0f / (float)max(v[i], 1);
            excl += v[i];
        }
    }
    if (blockIdx.x == 0 && t == 0) offs[NN] = NE;
}

__global__ void k_fill(const int* __restrict__ ei, int* __restrict__ cur, int* __restrict__ esrc) {
    int e = blockIdx.x * 256 + threadIdx.x;
    if (e < NE) {
        int d = ei[NE + e];
        int slot = atomicAdd(&cur[d], 1);
        esrc[slot] = ei[e];
    }
}

// ---------------- x -> bf16 cast ----------------

__global__ __launch_bounds__(256) void k_cast(const float* __restrict__ x, unsigned int* __restrict__ o) {
    size_t i = (size_t)blockIdx.x * 256 + threadIdx.x;   // u32 index, NN*64 total
    float2 v = ((const float2*)x)[i];
    o[i] = pack_bf2(v.x, v.y);
}

// ---------------- weight transpose+convert: W[k][f] f32 -> WT[f][kpair] bf16x2 ----------------

__global__ __launch_bounds__(256) void k_transW(const float* __restrict__ Wl, const float* __restrict__ Wr,
                                                unsigned int* __restrict__ WT) {
    int m = blockIdx.x;                       // 0..5: layer = m>>1, which = m&1
    const float* W = ((m & 1) ? Wr : Wl) + (size_t)(m >> 1) * DD * DD;
    unsigned int* o = WT + (size_t)m * DD * 64;
    for (int idx = threadIdx.x; idx < DD * 64; idx += 256) {
        int f = idx >> 6, kp = idx & 63;
        float w0 = W[(size_t)(2 * kp) * DD + f];
        float w1 = W[(size_t)(2 * kp + 1) * DD + f];
        o[idx] = pack_bf2(w0, w1);
    }
}

// ---------------- aggregation (bf16): one wave per node, 4 nodes/block, unroll 8 ----------------

__global__ __launch_bounds__(256) void k_agg(const unsigned int* __restrict__ hb,
                                             const int* __restrict__ offs,
                                             const int* __restrict__ esrc,
                                             const float* __restrict__ deg_inv,
                                             unsigned int* __restrict__ outb) {
    int n = blockIdx.x * 4 + (threadIdx.x >> 6);
    int t = threadIdx.x & 63;
    int s0 = offs[n], s1 = offs[n + 1];
    float ax = 0.f, ay = 0.f;
    int j = s0;
    for (; j + 7 < s1; j += 8) {
        unsigned int v[8];
        #pragma unroll
        for (int u = 0; u < 8; ++u) v[u] = hb[(size_t)esrc[j + u] * 64 + t];
        #pragma unroll
        for (int u = 0; u < 8; ++u) {
            float2 f = unpack_bf2(v[u]);
            ax += f.x; ay += f.y;
        }
    }
    for (; j < s1; ++j) {
        float2 f0 = unpack_bf2(hb[(size_t)esrc[j] * 64 + t]);
        ax += f0.x; ay += f0.y;
    }
    float di = deg_inv[n];
    outb[(size_t)n * 64 + t] = pack_bf2(ax * di, ay * di);
}

// ---------------- MFMA GEMM: persistent-weight blocks, LDS-staged swizzled weights ----------------
// 512 blocks x 256 thr (4 waves). Stage WlT+WrT (64 KB) into LDS once, XOR-swizzled.
// Each wave grid-strides over 16-node strips: out = agg@Wl + bl + h@Wr, bf16 out, BN stats via LDS atomics.

__global__ __launch_bounds__(256) void k_gemm_mfma(
    const unsigned short* __restrict__ aggb, const unsigned short* __restrict__ hb,
    const unsigned int* __restrict__ WlT, const unsigned int* __restrict__ WrT,  // [128 f][64 kpair]
    const float* __restrict__ bl,
    unsigned int* __restrict__ outp /* bf16 pairs */, float* __restrict__ bn /* [2][DD] */) {

    __shared__ unsigned int wlds[2][DD * 64];   // 2 x 32 KB, swizzled
    __shared__ float bnl[2 * DD];

    int tid = threadIdx.x;
    bnl[tid] = 0.f;

    // stage weights: uint4 chunk v -> row f=v>>4, chunk c=v&15, lds chunk = c ^ (f&7)
    #pragma unroll
    for (int m = 0; m < 2; ++m) {
        const uint4* src = (const uint4*)(m ? WrT : WlT);
        uint4* dst = (uint4*)wlds[m];
        #pragma unroll
        for (int i = 0; i < 8; ++i) {
            int v = i * 256 + tid;          // 0..2047
            int f = v >> 4, c = v & 15;
            dst[f * 16 + (c ^ (f & 7))] = src[v];
        }
    }
    __syncthreads();

    int wid = blockIdx.x * 4 + (tid >> 6);
    int l = tid & 63;
    int r = l & 15;        // A row / D col within fragment
    int q = l >> 4;        // k-chunk quad (in) / row-quad (out)

    for (int s = wid; s < NSTRIP; s += GEMM_WAVES) {
        int n0 = s * 16;
        f4v acc[8];
        #pragma unroll
        for (int cf = 0; cf < 8; ++cf) acc[cf] = (f4v){0.f, 0.f, 0.f, 0.f};

        #pragma unroll
        for (int ks = 0; ks < 4; ++ks) {
            int kb = ks * 32 + q * 8;
            s8v a0 = *(const s8v*)(aggb + (size_t)(n0 + r) * DD + kb);
            s8v h0 = *(const s8v*)(hb   + (size_t)(n0 + r) * DD + kb);
            #pragma unroll
            for (int cf = 0; cf < 8; ++cf) {
                int col = cf * 16 + r;
                int wo = col * 64 + (((ks * 4 + q) ^ (r & 7)) * 4);   // u32 index, swizzled
                s8v wl = *(const s8v*)&wlds[0][wo];
                s8v wr = *(const s8v*)&wlds[1][wo];
                acc[cf] = __builtin_amdgcn_mfma_f32_16x16x32_bf16(a0, wl, acc[cf], 0, 0, 0);
                acc[cf] = __builtin_amdgcn_mfma_f32_16x16x32_bf16(h0, wr, acc[cf], 0, 0, 0);
            }
        }

        // epilogue: bias, BN partials (LDS atomics), bf16-pair store via shfl pack
        #pragma unroll
        for (int cf = 0; cf < 8; ++cf) {
            int col = cf * 16 + r;
            float b = bl[col];
            float v[4]; float s1 = 0.f, s2 = 0.f;
            #pragma unroll
            for (int j = 0; j < 4; ++j) {
                v[j] = acc[cf][j] + b;
                s1 += v[j]; s2 += v[j] * v[j];
            }
            float t1 = s1, t2 = s2;
            t1 += __shfl_xor(t1, 16); t1 += __shfl_xor(t1, 32);
            t2 += __shfl_xor(t2, 16); t2 += __shfl_xor(t2, 32);
            if (q == 0) {
                atomicAdd(&bnl[col], t1);
                atomicAdd(&bnl[DD + col], t2);
            }
            float p[4];
            #pragma unroll
            for (int j = 0; j < 4; ++j) p[j] = __shfl_xor(v[j], 1);
            if (!(r & 1)) {
                #pragma unroll
                for (int j = 0; j < 4; ++j) {
                    int n = n0 + q * 4 + j;
                    outp[(size_t)n * 64 + cf * 8 + (r >> 1)] = pack_bf2(v[j], p[j]);
                }
            }
        }
    }

    __syncthreads();
    atomicAdd(&bn[tid], bnl[tid]);   // tid 0..255 covers [2][DD]
}

// ---------------- BN finalize + apply(+ReLU) -> bf16 ----------------

__global__ void k_bnfinal(const float* __restrict__ bn, const float* __restrict__ gamma,
                          const float* __restrict__ beta, float* __restrict__ ss) {
    int f = threadIdx.x;
    float mu = bn[f] / (float)NN;
    float var = bn[DD + f] / (float)NN - mu * mu;
    var = fmaxf(var, 0.f);
    float sc = gamma[f] * rsqrtf(var + EPSV);
    ss[f] = sc;
    ss[DD + f] = beta[f] - mu * sc;
}

__global__ __launch_bounds__(256) void k_bnrelu(const unsigned int* __restrict__ gout,
                                                const float* __restrict__ ss,
                                                unsigned int* __restrict__ hb) {
    size_t i = (size_t)blockIdx.x * 256 + threadIdx.x;   // u32 index, NN*64 total
    int fp = (int)(i & 63);                              // feature pair
    float2 v  = unpack_bf2(gout[i]);
    float2 sc = ((const float2*)ss)[fp];
    float2 sh = ((const float2*)(ss + DD))[fp];
    float a = fmaxf(v.x * sc.x + sh.x, 0.f);
    float b = fmaxf(v.y * sc.y + sh.y, 0.f);
    hb[i] = pack_bf2(a, b);
}

// ---------------- pooling: wave-per-slab over sorted batch, flush on graph change ----------------

__global__ __launch_bounds__(64) void k_pool(const unsigned int* __restrict__ hb,
                                             const int* __restrict__ batch,
                                             float* __restrict__ pool) {
    const int chunk = (NN + PB - 1) / PB;   // 49
    int start = blockIdx.x * chunk;
    if (start >= NN) return;
    int end = min(start + chunk, NN);
    int t = threadIdx.x;
    int cur = batch[start];
    float ax = 0.f, ay = 0.f;
    for (int n = start; n < end; ++n) {
        int g = batch[n];
        if (g != cur) {
            atomicAdd(&pool[cur * DD + 2 * t], ax);
            atomicAdd(&pool[cur * DD + 2 * t + 1], ay);
            ax = 0.f; ay = 0.f; cur = g;
        }
        float2 f = unpack_bf2(hb[(size_t)n * 64 + t]);
        ax += f.x; ay += f.y;
    }
    atomicAdd(&pool[cur * DD + 2 * t], ax);
    atomicAdd(&pool[cur * DD + 2 * t + 1], ay);
}

// ---------------- classifier ----------------

__device__ int lbound(const int* __restrict__ a, int v) {
    int lo = 0, hi = NN;
    while (lo < hi) { int m = (lo + hi) >> 1; if (a[m] < v) lo = m + 1; else hi = m; }
    return lo;
}

__global__ __launch_bounds__(128) void k_cls(const float* __restrict__ pool, const int* __restrict__ batch,
                                             const float* __restrict__ Wc, const float* __restrict__ bc,
                                             float* __restrict__ outp) {
    __shared__ float emb[DD];
    int g = blockIdx.x; int t = threadIdx.x;
    int s0 = lbound(batch, g);
    int e0 = lbound(batch, g + 1);
    float cnt = fmaxf((float)(e0 - s0), 1.f);
    emb[t] = pool[g * DD + t] / cnt;
    __syncthreads();
    if (t < NC) {
        float s = bc[t];
        for (int k = 0; k < DD; k++) s += emb[k] * Wc[k * NC + t];
        outp[g * NC + t] = s;
    }
}

// ---------------- launcher ----------------

extern "C" void kernel_launch(void* const* d_in, const int* in_sizes, int n_in,
                              void* d_out, int out_size, void* d_ws, size_t ws_size,
                              hipStream_t stream) {
    const float* x     = (const float*)d_in[0];
    const int*   ei    = (const int*)d_in[1];
    const int*   batch = (const int*)d_in[2];
    const float* Wl    = (const float*)d_in[3];
    const float* bl    = (const float*)d_in[4];
    const float* Wr    = (const float*)d_in[5];
    const float* gamma = (const float*)d_in[6];
    const float* beta  = (const float*)d_in[7];
    const float* Wc    = (const float*)d_in[8];
    const float* bc    = (const float*)d_in[9];
    float* outp = (float*)d_out;

    char* p = (char*)d_ws;
    auto alloc = [&](size_t bytes) { char* r = p; p += (bytes + 255) & ~(size_t)255; return r; };
    unsigned int* bufA = (unsigned int*)alloc((size_t)NN * 64 * 4);   // h (bf16 pairs)
    unsigned int* bufB = (unsigned int*)alloc((size_t)NN * 64 * 4);   // agg scratch (bf16 pairs)
    unsigned int* gout = (unsigned int*)alloc((size_t)NN * 64 * 4);   // gemm out (bf16 pairs)
    unsigned int* WT = (unsigned int*)alloc((size_t)NL * 2 * DD * 64 * 4);
    float* deg_inv = (float*)alloc((size_t)NN * 4);
    int*   csr_off = (int*)alloc((size_t)(NN + 1) * 4);
    int*   csr_cur = (int*)alloc((size_t)NN * 4);
    int*   esrc    = (int*)alloc((size_t)NE * 4);
    int*   part    = (int*)alloc(1024 * 4);
    float* bn      = (float*)alloc(2 * DD * 4);
    float* ss      = (float*)alloc(2 * DD * 4);
    float* pool    = (float*)alloc((size_t)NG * DD * 4);

    hipMemsetAsync(csr_cur, 0, (size_t)NN * 4, stream);
    hipMemsetAsync(pool, 0, (size_t)NG * DD * 4, stream);

    k_hist<<<NE / 256, 256, 0, stream>>>(ei, csr_cur);
    k_scan_part<<<NB_SCAN, 256, 0, stream>>>(csr_cur, part);
    k_scan_top<<<1, 128, 0, stream>>>(part, NB_SCAN);
    k_scan_final<<<NB_SCAN, 256, 0, stream>>>(part, csr_cur, csr_off, deg_inv);
    k_fill<<<NE / 256, 256, 0, stream>>>(ei, csr_cur, esrc);

    k_cast<<<NN * 64 / 256, 256, 0, stream>>>(x, bufA);
    k_transW<<<NL * 2, 256, 0, stream>>>(Wl, Wr, WT);

    for (int l = 0; l < NL; l++) {
        hipMemsetAsync(bn, 0, 2 * DD * 4, stream);
        k_agg<<<NN / 4, 256, 0, stream>>>(bufA, csr_off, esrc, deg_inv, bufB);
        const unsigned int* WlT = WT + (size_t)(2 * l) * DD * 64;
        const unsigned int* WrT = WT + (size_t)(2 * l + 1) * DD * 64;
        k_gemm_mfma<<<GEMM_BLOCKS, 256, 0, stream>>>((const unsigned short*)bufB, (const unsigned short*)bufA,
                                                     WlT, WrT, bl + (size_t)l * DD, gout, bn);
        k_bnfinal<<<1, 128, 0, stream>>>(bn, gamma + (size_t)l * DD, beta + (size_t)l * DD, ss);
        k_bnrelu<<<NN * 64 / 256, 256, 0, stream>>>(gout, ss, bufA);
    }

    k_pool<<<PB, 64, 0, stream>>>(bufA, batch, pool);
    k_cls<<<NG, 128, 0, stream>>>(pool, batch, Wc, bc, outp);
}

// Round 16
// 539.637 us; speedup vs baseline: 1.9105x; 1.0958x over previous
//
#include <hip/hip_runtime.h>

#define NN 100000      // nodes
#define NE 800000      // edges
#define DD 128         // hidden dim
#define NL 3           // layers
#define NC 10          // classes
#define NG 64          // graphs
#define EPSV 1e-5f
#define SCAN_CHUNK 1024
#define NB_SCAN ((NN + SCAN_CHUNK - 1) / SCAN_CHUNK)   // 98
#define PB 2048        // pooling waves
#define NSTRIP (NN / 16)   // 6250 16-node strips
#define GEMM_BLOCKS 512
#define GEMM_WAVES (GEMM_BLOCKS * 4)

typedef short s8v __attribute__((ext_vector_type(8)));   // 8 bf16 (4 VGPRs)
typedef float f4v __attribute__((ext_vector_type(4)));   // mfma accumulator

// ---- bf16 pack/unpack helpers (RNE) ----
__device__ inline unsigned int pack_bf2(float a, float b) {
    unsigned int ua = __float_as_uint(a); ua += 0x7fffu + ((ua >> 16) & 1u);
    unsigned int ub = __float_as_uint(b); ub += 0x7fffu + ((ub >> 16) & 1u);
    return (ua >> 16) | (ub & 0xffff0000u);
}
__device__ inline float2 unpack_bf2(unsigned int v) {
    return make_float2(__uint_as_float(v << 16), __uint_as_float(v & 0xffff0000u));
}

// ---------------- CSR build ----------------

__global__ void k_hist(const int* __restrict__ ei, int* __restrict__ cnt) {
    int e = blockIdx.x * 256 + threadIdx.x;
    if (e < NE) atomicAdd(&cnt[ei[NE + e]], 1);
}

__global__ void k_scan_part(const int* __restrict__ cnt, int* __restrict__ part) {
    __shared__ int lds[256];
    int base = blockIdx.x * SCAN_CHUNK + threadIdx.x * 4;
    int s = 0;
    for (int i = 0; i < 4; i++) { int idx = base + i; if (idx < NN) s += cnt[idx]; }
    lds[threadIdx.x] = s; __syncthreads();
    for (int off = 128; off > 0; off >>= 1) {
        if (threadIdx.x < off) lds[threadIdx.x] += lds[threadIdx.x + off];
        __syncthreads();
    }
    if (threadIdx.x == 0) part[blockIdx.x] = lds[0];
}

__global__ void k_scan_top(int* part, int nb) {
    __shared__ int lds[128];
    int t = threadIdx.x;
    int v = (t < nb) ? part[t] : 0;
    lds[t] = v; __syncthreads();
    for (int off = 1; off < 128; off <<= 1) {
        int add = (t >= off) ? lds[t - off] : 0;
        __syncthreads();
        lds[t] += add;
        __syncthreads();
    }
    if (t < nb) part[t] = lds[t] - v;   // exclusive
}

__global__ void k_scan_final(const int* __restrict__ part, int* __restrict__ cnt,
                             int* __restrict__ offs, float* __restrict__ deg_inv) {
    __shared__ int lds[256];
    int t = threadIdx.x;
    int base = blockIdx.x * SCAN_CHUNK + t * 4;
    int v[4]; int s = 0;
    for (int i = 0; i < 4; i++) { int idx = base + i; v[i] = (idx < NN) ? cnt[idx] : 0; s += v[i]; }
    lds[t] = s; __syncthreads();
    for (int o = 1; o < 256; o <<= 1) {
        int add = (t >= o) ? lds[t - o] : 0;
        __syncthreads();
        lds[t] += add;
        __syncthreads();
    }
    int excl = lds[t] - s + part[blockIdx.x];
    for (int i = 0; i < 4; i++) {
        int idx = base + i;
        if (idx < NN) {
            offs[idx] = excl;
            cnt[idx]  = excl;   // becomes the fill cursor
            deg_inv[idx] = 1.0f / (float)max(v[i], 1);
            excl += v[i];
        }
    }
    if (blockIdx.x == 0 && t == 0) offs[NN] = NE;
}

__global__ void k_fill(const int* __restrict__ ei, int* __restrict__ cur, int* __restrict__ esrc) {
    int e = blockIdx.x * 256 + threadIdx.x;
    if (e < NE) {
        int d = ei[NE + e];
        int slot = atomicAdd(&cur[d], 1);
        esrc[slot] = ei[e];
    }
}

// ---------------- x -> bf16 cast ----------------

__global__ __launch_bounds__(256) void k_cast(const float* __restrict__ x, unsigned int* __restrict__ o) {
    size_t i = (size_t)blockIdx.x * 256 + threadIdx.x;   // u32 index, NN*64 total
    float2 v = ((const float2*)x)[i];
    o[i] = pack_bf2(v.x, v.y);
}

// ---------------- weight transpose+convert: W[k][f] f32 -> WT[f][kpair] bf16x2 ----------------

__global__ __launch_bounds__(256) void k_transW(const float* __restrict__ Wl, const float* __restrict__ Wr,
                                                unsigned int* __restrict__ WT) {
    int m = blockIdx.x;                       // 0..5: layer = m>>1, which = m&1
    const float* W = ((m & 1) ? Wr : Wl) + (size_t)(m >> 1) * DD * DD;
    unsigned int* o = WT + (size_t)m * DD * 64;
    for (int idx = threadIdx.x; idx < DD * 64; idx += 256) {
        int f = idx >> 6, kp = idx & 63;
        float w0 = W[(size_t)(2 * kp) * DD + f];
        float w1 = W[(size_t)(2 * kp + 1) * DD + f];
        o[idx] = pack_bf2(w0, w1);
    }
}

// ---------------- aggregation (bf16): wave/node; predicated 8-deep gather (full MLP on tails) ------

__global__ __launch_bounds__(256) void k_agg(const unsigned int* __restrict__ hb,
                                             const int* __restrict__ offs,
                                             const int* __restrict__ esrc,
                                             const float* __restrict__ deg_inv,
                                             unsigned int* __restrict__ outb) {
    int n = blockIdx.x * 4 + (threadIdx.x >> 6);
    int t = threadIdx.x & 63;
    int s0 = offs[n], s1 = offs[n + 1];
    float ax = 0.f, ay = 0.f;
    int last = s1 - 1;
    for (int j = s0; j < s1; j += 8) {
        unsigned int v[8];
        #pragma unroll
        for (int u = 0; u < 8; ++u) {
            int jj = j + u;
            int e = esrc[jj <= last ? jj : last];   // clamped: load always issues
            v[u] = hb[(size_t)e * 64 + t];
        }
        #pragma unroll
        for (int u = 0; u < 8; ++u) {
            float2 f = unpack_bf2(v[u]);
            bool ok = (j + u < s1);
            ax += ok ? f.x : 0.f;                   // cndmask, no branch
            ay += ok ? f.y : 0.f;
        }
    }
    float di = deg_inv[n];
    outb[(size_t)n * 64 + t] = pack_bf2(ax * di, ay * di);
}

// ---------------- MFMA GEMM: persistent-weight blocks, LDS-staged swizzled weights ----------------
// 512 blocks x 256 thr (4 waves). Stage WlT+WrT (64 KB) into LDS once, XOR-swizzled.
// Each wave grid-strides over 16-node strips: out = agg@Wl + bl + h@Wr, bf16 out, BN stats via LDS atomics.

__global__ __launch_bounds__(256) void k_gemm_mfma(
    const unsigned short* __restrict__ aggb, const unsigned short* __restrict__ hb,
    const unsigned int* __restrict__ WlT, const unsigned int* __restrict__ WrT,  // [128 f][64 kpair]
    const float* __restrict__ bl,
    unsigned int* __restrict__ outp /* bf16 pairs */, float* __restrict__ bn /* [2][DD] */) {

    __shared__ unsigned int wlds[2][DD * 64];   // 2 x 32 KB, swizzled
    __shared__ float bnl[2 * DD];

    int tid = threadIdx.x;
    bnl[tid] = 0.f;

    // stage weights: uint4 chunk v -> row f=v>>4, chunk c=v&15, lds chunk = c ^ (f&7)
    #pragma unroll
    for (int m = 0; m < 2; ++m) {
        const uint4* src = (const uint4*)(m ? WrT : WlT);
        uint4* dst = (uint4*)wlds[m];
        #pragma unroll
        for (int i = 0; i < 8; ++i) {
            int v = i * 256 + tid;          // 0..2047
            int f = v >> 4, c = v & 15;
            dst[f * 16 + (c ^ (f & 7))] = src[v];
        }
    }
    __syncthreads();

    int wid = blockIdx.x * 4 + (tid >> 6);
    int l = tid & 63;
    int r = l & 15;        // A row / D col within fragment
    int q = l >> 4;        // k-chunk quad (in) / row-quad (out)

    for (int s = wid; s < NSTRIP; s += GEMM_WAVES) {
        int n0 = s * 16;
        f4v acc[8];
        #pragma unroll
        for (int cf = 0; cf < 8; ++cf) acc[cf] = (f4v){0.f, 0.f, 0.f, 0.f};

        #pragma unroll
        for (int ks = 0; ks < 4; ++ks) {
            int kb = ks * 32 + q * 8;
            s8v a0 = *(const s8v*)(aggb + (size_t)(n0 + r) * DD + kb);
            s8v h0 = *(const s8v*)(hb   + (size_t)(n0 + r) * DD + kb);
            #pragma unroll
            for (int cf = 0; cf < 8; ++cf) {
                int col = cf * 16 + r;
                int wo = col * 64 + (((ks * 4 + q) ^ (r & 7)) * 4);   // u32 index, swizzled
                s8v wl = *(const s8v*)&wlds[0][wo];
                s8v wr = *(const s8v*)&wlds[1][wo];
                acc[cf] = __builtin_amdgcn_mfma_f32_16x16x32_bf16(a0, wl, acc[cf], 0, 0, 0);
                acc[cf] = __builtin_amdgcn_mfma_f32_16x16x32_bf16(h0, wr, acc[cf], 0, 0, 0);
            }
        }

        // epilogue: bias, BN partials (LDS atomics), bf16-pair store via shfl pack
        #pragma unroll
        for (int cf = 0; cf < 8; ++cf) {
            int col = cf * 16 + r;
            float b = bl[col];
            float v[4]; float s1 = 0.f, s2 = 0.f;
            #pragma unroll
            for (int j = 0; j < 4; ++j) {
                v[j] = acc[cf][j] + b;
                s1 += v[j]; s2 += v[j] * v[j];
            }
            float t1 = s1, t2 = s2;
            t1 += __shfl_xor(t1, 16); t1 += __shfl_xor(t1, 32);
            t2 += __shfl_xor(t2, 16); t2 += __shfl_xor(t2, 32);
            if (q == 0) {
                atomicAdd(&bnl[col], t1);
                atomicAdd(&bnl[DD + col], t2);
            }
            float p[4];
            #pragma unroll
            for (int j = 0; j < 4; ++j) p[j] = __shfl_xor(v[j], 1);
            if (!(r & 1)) {
                #pragma unroll
                for (int j = 0; j < 4; ++j) {
                    int n = n0 + q * 4 + j;
                    outp[(size_t)n * 64 + cf * 8 + (r >> 1)] = pack_bf2(v[j], p[j]);
                }
            }
        }
    }

    __syncthreads();
    atomicAdd(&bn[tid], bnl[tid]);   // tid 0..255 covers [2][DD]
}

// ---------------- BN finalize + apply(+ReLU) -> bf16 ----------------

__global__ void k_bnfinal(const float* __restrict__ bn, const float* __restrict__ gamma,
                          const float* __restrict__ beta, float* __restrict__ ss) {
    int f = threadIdx.x;
    float mu = bn[f] / (float)NN;
    float var = bn[DD + f] / (float)NN - mu * mu;
    var = fmaxf(var, 0.f);
    float sc = gamma[f] * rsqrtf(var + EPSV);
    ss[f] = sc;
    ss[DD + f] = beta[f] - mu * sc;
}

__global__ __launch_bounds__(256) void k_bnrelu(const unsigned int* __restrict__ gout,
                                                const float* __restrict__ ss,
                                                unsigned int* __restrict__ hb) {
    size_t i = (size_t)blockIdx.x * 256 + threadIdx.x;   // u32 index, NN*64 total
    int fp = (int)(i & 63);                              // feature pair
    float2 v  = unpack_bf2(gout[i]);
    float2 sc = ((const float2*)ss)[fp];
    float2 sh = ((const float2*)(ss + DD))[fp];
    float a = fmaxf(v.x * sc.x + sh.x, 0.f);
    float b = fmaxf(v.y * sc.y + sh.y, 0.f);
    hb[i] = pack_bf2(a, b);
}

// ---------------- pooling: wave-per-slab over sorted batch, flush on graph change ----------------

__global__ __launch_bounds__(64) void k_pool(const unsigned int* __restrict__ hb,
                                             const int* __restrict__ batch,
                                             float* __restrict__ pool) {
    const int chunk = (NN + PB - 1) / PB;   // 49
    int start = blockIdx.x * chunk;
    if (start >= NN) return;
    int end = min(start + chunk, NN);
    int t = threadIdx.x;
    int cur = batch[start];
    float ax = 0.f, ay = 0.f;
    for (int n = start; n < end; ++n) {
        int g = batch[n];
        if (g != cur) {
            atomicAdd(&pool[cur * DD + 2 * t], ax);
            atomicAdd(&pool[cur * DD + 2 * t + 1], ay);
            ax = 0.f; ay = 0.f; cur = g;
        }
        float2 f = unpack_bf2(hb[(size_t)n * 64 + t]);
        ax += f.x; ay += f.y;
    }
    atomicAdd(&pool[cur * DD + 2 * t], ax);
    atomicAdd(&pool[cur * DD + 2 * t + 1], ay);
}

// ---------------- classifier ----------------

__device__ int lbound(const int* __restrict__ a, int v) {
    int lo = 0, hi = NN;
    while (lo < hi) { int m = (lo + hi) >> 1; if (a[m] < v) lo = m + 1; else hi = m; }
    return lo;
}

__global__ __launch_bounds__(128) void k_cls(const float* __restrict__ pool, const int* __restrict__ batch,
                                             const float* __restrict__ Wc, const float* __restrict__ bc,
                                             float* __restrict__ outp) {
    __shared__ float emb[DD];
    int g = blockIdx.x; int t = threadIdx.x;
    int s0 = lbound(batch, g);
    int e0 = lbound(batch, g + 1);
    float cnt = fmaxf((float)(e0 - s0), 1.f);
    emb[t] = pool[g * DD + t] / cnt;
    __syncthreads();
    if (t < NC) {
        float s = bc[t];
        for (int k = 0; k < DD; k++) s += emb[k] * Wc[k * NC + t];
        outp[g * NC + t] = s;
    }
}

// ---------------- launcher ----------------

extern "C" void kernel_launch(void* const* d_in, const int* in_sizes, int n_in,
                              void* d_out, int out_size, void* d_ws, size_t ws_size,
                              hipStream_t stream) {
    const float* x     = (const float*)d_in[0];
    const int*   ei    = (const int*)d_in[1];
    const int*   batch = (const int*)d_in[2];
    const float* Wl    = (const float*)d_in[3];
    const float* bl    = (const float*)d_in[4];
    const float* Wr    = (const float*)d_in[5];
    const float* gamma = (const float*)d_in[6];
    const float* beta  = (const float*)d_in[7];
    const float* Wc    = (const float*)d_in[8];
    const float* bc    = (const float*)d_in[9];
    float* outp = (float*)d_out;

    char* p = (char*)d_ws;
    auto alloc = [&](size_t bytes) { char* r = p; p += (bytes + 255) & ~(size_t)255; return r; };
    unsigned int* bufA = (unsigned int*)alloc((size_t)NN * 64 * 4);   // h (bf16 pairs)
    unsigned int* bufB = (unsigned int*)alloc((size_t)NN * 64 * 4);   // agg scratch (bf16 pairs)
    unsigned int* gout = (unsigned int*)alloc((size_t)NN * 64 * 4);   // gemm out (bf16 pairs)
    unsigned int* WT = (unsigned int*)alloc((size_t)NL * 2 * DD * 64 * 4);
    float* deg_inv = (float*)alloc((size_t)NN * 4);
    int*   csr_off = (int*)alloc((size_t)(NN + 1) * 4);
    int*   csr_cur = (int*)alloc((size_t)NN * 4);
    int*   esrc    = (int*)alloc((size_t)NE * 4);
    int*   part    = (int*)alloc(1024 * 4);
    float* bn      = (float*)alloc(2 * DD * 4);
    float* ss      = (float*)alloc(2 * DD * 4);
    float* pool    = (float*)alloc((size_t)NG * DD * 4);

    hipMemsetAsync(csr_cur, 0, (size_t)NN * 4, stream);
    hipMemsetAsync(pool, 0, (size_t)NG * DD * 4, stream);

    k_hist<<<NE / 256, 256, 0, stream>>>(ei, csr_cur);
    k_scan_part<<<NB_SCAN, 256, 0, stream>>>(csr_cur, part);
    k_scan_top<<<1, 128, 0, stream>>>(part, NB_SCAN);
    k_scan_final<<<NB_SCAN, 256, 0, stream>>>(part, csr_cur, csr_off, deg_inv);
    k_fill<<<NE / 256, 256, 0, stream>>>(ei, csr_cur, esrc);

    k_cast<<<NN * 64 / 256, 256, 0, stream>>>(x, bufA);
    k_transW<<<NL * 2, 256, 0, stream>>>(Wl, Wr, WT);

    for (int l = 0; l < NL; l++) {
        hipMemsetAsync(bn, 0, 2 * DD * 4, stream);
        k_agg<<<NN / 4, 256, 0, stream>>>(bufA, csr_off, esrc, deg_inv, bufB);
        const unsigned int* WlT = WT + (size_t)(2 * l) * DD * 64;
        const unsigned int* WrT = WT + (size_t)(2 * l + 1) * DD * 64;
        k_gemm_mfma<<<GEMM_BLOCKS, 256, 0, stream>>>((const unsigned short*)bufB, (const unsigned short*)bufA,
                                                     WlT, WrT, bl + (size_t)l * DD, gout, bn);
        k_bnfinal<<<1, 128, 0, stream>>>(bn, gamma + (size_t)l * DD, beta + (size_t)l * DD, ss);
        k_bnrelu<<<NN * 64 / 256, 256, 0, stream>>>(gout, ss, bufA);
    }

    k_pool<<<PB, 64, 0, stream>>>(bufA, batch, pool);
    k_cls<<<NG, 128, 0, stream>>>(pool, batch, Wc, bc, outp);
}